// Round 1
// baseline (565.404 us; speedup 1.0000x reference)
//
#include <hip/hip_runtime.h>

// MHA forward, MI355X/gfx950.
// B=2, S=2048, D_MODEL=2048, H=16, DK=128. All GEMMs bf16-MFMA (16x16x32),
// fp32 accumulate. Weights are W[e][d] == B^T, so every GEMM is the verified
// "gemm_bt" shape (A[M][K] x W[N][K]^T).
//
// Workspace layout (96 MiB needed):
//   [0,16M)   xb   : x cast to bf16  (later reused as attention output)
//   [16,24M)  wq_b16, [24,32M) wk_b16, [32,40M) wv_b16, [40,48M) wo_b16
//   [48,64M)  Q bf16, [64,80M) K bf16, [80,96M) V bf16   (token-major [tok][h*128+d])

#define DMODEL 2048
#define SEQ    2048
#define NHEAD  16
#define DKH    128
#define NBATCH 2
#define MTOK   (NBATCH*SEQ)   // 4096

typedef float  f32x4  __attribute__((ext_vector_type(4)));
typedef __bf16 bf16x8 __attribute__((ext_vector_type(8)));
typedef unsigned short      u16;
typedef unsigned short      u16x8 __attribute__((ext_vector_type(8)));

__device__ __forceinline__ float b2f(u16 u) {
    union { unsigned i; float f; } x; x.i = ((unsigned)u) << 16; return x.f;
}
__device__ __forceinline__ u16 f2bf(float f) {  // round-to-nearest-even
    union { float f; unsigned i; } x; x.f = f;
    unsigned r = x.i + 0x7fffu + ((x.i >> 16) & 1u);
    return (u16)(r >> 16);
}

// async global->LDS, 16B per lane; LDS dest is wave-uniform base + lane*16
__device__ __forceinline__ void load_lds16(const void* g, void* l) {
    __builtin_amdgcn_global_load_lds(
        (const __attribute__((address_space(1))) void*)g,
        (__attribute__((address_space(3))) void*)l, 16, 0, 0);
}

// ---------------------------------------------------------------- cast f32->bf16
__global__ void cast_f2b_kernel(const float* __restrict__ in, u16* __restrict__ out, int n4) {
    int i = blockIdx.x * blockDim.x + threadIdx.x;
    if (i >= n4) return;
    float4 f = ((const float4*)in)[i];
    uint2 o;
    o.x = (unsigned)f2bf(f.x) | ((unsigned)f2bf(f.y) << 16);
    o.y = (unsigned)f2bf(f.z) | ((unsigned)f2bf(f.w) << 16);
    ((uint2*)out)[i] = o;
}

// ---------------------------------------------------------------- GEMM (B^T form)
// C[M][N] = A[M][K] * W[N][K]^T + bias.  128x128 tile, BK=64, 4 waves (2x2),
// each wave 64x64 via 4x4 MFMA 16x16x32 tiles. LDS chunks (16B) XOR-swizzled:
// logical chunk c of row r lives at physical c ^ (r&7)  -> frag reads are
// 2-way bank aliased only (free).
template<bool BF16_OUT>
__global__ __launch_bounds__(256) void gemm_bt(
    const u16* __restrict__ A, const u16* __restrict__ W,
    const float* __restrict__ bias, void* __restrict__ Cout,
    int M, int N, int K)
{
    __shared__ u16 As[128 * 64];
    __shared__ u16 Bs[128 * 64];
    const int tid  = threadIdx.x;
    const int lane = tid & 63;
    const int w    = tid >> 6;
    const int wm   = w >> 1, wn = w & 1;
    const int quad = lane >> 4, l16 = lane & 15;
    const int row0 = blockIdx.y * 128;
    const int col0 = blockIdx.x * 128;

    f32x4 acc[4][4] = {};

    for (int kt = 0; kt < K / 64; ++kt) {
        const int k0 = kt * 64;
#pragma unroll
        for (int i = 0; i < 4; ++i) {
            int cb = (i * 4 + w) * 64;        // wave-uniform physical chunk base
            int p  = cb + lane;               // physical 16B chunk this lane fills
            int r  = p >> 3;                  // tile row
            int cl = (p & 7) ^ (r & 7);       // logical chunk to fetch
            load_lds16(A + (size_t)(row0 + r) * K + k0 + cl * 8, (void*)(As + cb * 8));
            load_lds16(W + (size_t)(col0 + r) * K + k0 + cl * 8, (void*)(Bs + cb * 8));
        }
        __syncthreads();
#pragma unroll
        for (int ks = 0; ks < 2; ++ks) {
            bf16x8 af[4], bfr[4];
#pragma unroll
            for (int mi = 0; mi < 4; ++mi) {
                int r  = wm * 64 + mi * 16 + l16;
                int pc = (ks * 4 + quad) ^ (r & 7);
                af[mi] = *(const bf16x8*)(As + (r * 8 + pc) * 8);
            }
#pragma unroll
            for (int ni = 0; ni < 4; ++ni) {
                int r  = wn * 64 + ni * 16 + l16;
                int pc = (ks * 4 + quad) ^ (r & 7);
                bfr[ni] = *(const bf16x8*)(Bs + (r * 8 + pc) * 8);
            }
#pragma unroll
            for (int mi = 0; mi < 4; ++mi)
#pragma unroll
                for (int ni = 0; ni < 4; ++ni)
                    acc[mi][ni] = __builtin_amdgcn_mfma_f32_16x16x32_bf16(
                        af[mi], bfr[ni], acc[mi][ni], 0, 0, 0);
        }
        __syncthreads();
    }
    // epilogue: C/D layout col=lane&15, row=quad*4+reg  [m89/m91 verified]
#pragma unroll
    for (int mi = 0; mi < 4; ++mi) {
#pragma unroll
        for (int ni = 0; ni < 4; ++ni) {
            int col = col0 + wn * 64 + ni * 16 + l16;
            float bv = bias[col];
#pragma unroll
            for (int r = 0; r < 4; ++r) {
                int row = row0 + wm * 64 + mi * 16 + quad * 4 + r;
                float v = acc[mi][ni][r] + bv;
                if (BF16_OUT) ((u16*)Cout)[(size_t)row * N + col] = f2bf(v);
                else          ((float*)Cout)[(size_t)row * N + col] = v;
            }
        }
    }
}

// ---------------------------------------------------------------- RoPE (in-place)
// One thread per (token, head, freq-pair). blockIdx.y: 0->Q (also folds 1/sqrt(DK)
// score scale into Q), 1->K. Coalesced 4B pair load/store.
__global__ void rope_kernel(u16* __restrict__ Q, u16* __restrict__ Kt) {
    int idx = blockIdx.x * blockDim.x + threadIdx.x;   // < MTOK*NHEAD*64
    u16* P      = blockIdx.y ? Kt : Q;
    float scale = blockIdx.y ? 1.0f : 0.08838834764831845f;  // 1/sqrt(128)
    int i   = idx & 63;          // frequency index
    int tok = idx >> 10;         // (h*64+i) packs into 10 bits
    int s   = tok & (SEQ - 1);
    unsigned pr = *(const unsigned*)(P + 2 * (size_t)idx);
    float e = b2f((u16)(pr & 0xffff)), o = b2f((u16)(pr >> 16));
    // inv_freq = 10000^(-i/64) = 2^(-log2(10000)*i/64)
    float inv_freq = exp2f(-13.287712379549449f * (float)i * (1.0f / 64.0f));
    float ang = (float)s * inv_freq;
    float c, sn;
    sincosf(ang, &sn, &c);
    float re = (e * c - o * sn) * scale;
    float ro = (e * sn + o * c) * scale;
    *(unsigned*)(P + 2 * (size_t)idx) = (unsigned)f2bf(re) | ((unsigned)f2bf(ro) << 16);
}

// ---------------------------------------------------------------- flash attention
// One block = (b, h, 64 q-rows). 4 waves, wave w owns q-rows [q0+16w, q0+16w+16):
// fully independent online softmax per wave (no cross-wave merge).
// K tile (64x128) staged via global_load_lds with 16-chunk XOR swizzle;
// V tile staged TRANSPOSED (Vt[d][key], ld=72 pad) so PV B-frags are ds_read_b128;
// P goes C-layout -> A-layout through per-wave padded LDS (m120 pattern).
__global__ __launch_bounds__(256) void attn_kernel(
    const u16* __restrict__ Q, const u16* __restrict__ Kg,
    const u16* __restrict__ Vg, u16* __restrict__ Out)
{
    const int qt = blockIdx.x;           // q-tile (64 rows)
    const int bh = blockIdx.y;
    const int b  = bh >> 4, h = bh & 15;
    const int q0 = qt * 64;

    __shared__ u16 Ks[64 * 128];         // swizzled, 16 KB
    __shared__ u16 Vt[128 * 72];         // transposed + pad, 18 KB
    __shared__ u16 Ps[4][16 * 72];       // per-wave P buffer, 9 KB

    const int tid  = threadIdx.x;
    const int lane = tid & 63;
    const int w    = tid >> 6;
    const int quad = lane >> 4, l16 = lane & 15;

    // Q fragments for this wave's 16 rows (A-operand: m=lane&15, k=quad*8+j)
    bf16x8 qf[4];
    const u16* qrow = Q + (size_t)(b * SEQ + q0 + w * 16 + l16) * DMODEL + h * DKH;
#pragma unroll
    for (int ks = 0; ks < 4; ++ks) qf[ks] = *(const bf16x8*)(qrow + ks * 32 + quad * 8);

    f32x4 o[8] = {};
    float m_r[4], l_r[4];
#pragma unroll
    for (int r = 0; r < 4; ++r) { m_r[r] = -1e30f; l_r[r] = 0.f; }

    for (int kt = 0; kt <= qt; ++kt) {
        const int k0 = kt * 64;
        // ---- stage K (async, swizzled: 16 chunks/row, phys = logical ^ (r&15))
#pragma unroll
        for (int i = 0; i < 4; ++i) {
            int cb = (i * 4 + w) * 64;
            int p  = cb + lane;
            int r  = p >> 4;
            int cl = (p & 15) ^ (r & 15);
            load_lds16(Kg + (size_t)(b * SEQ + k0 + r) * DMODEL + h * DKH + cl * 8,
                       (void*)(Ks + cb * 8));
        }
        // ---- stage V transposed
#pragma unroll
        for (int it = 0; it < 4; ++it) {
            int flat = it * 256 + tid;            // 0..1023
            int key = flat & 63, dblk = flat >> 6;
            u16x8 vv = *(const u16x8*)(Vg + (size_t)(b * SEQ + k0 + key) * DMODEL + h * DKH + dblk * 8);
#pragma unroll
            for (int j = 0; j < 8; ++j) Vt[(dblk * 8 + j) * 72 + key] = vv[j];
        }
        __syncthreads();

        // ---- S = Q K^T  (scale already folded into Q)
        f32x4 sc[4] = {};
#pragma unroll
        for (int ks = 0; ks < 4; ++ks) {
#pragma unroll
            for (int nt = 0; nt < 4; ++nt) {
                int r  = nt * 16 + l16;
                int pc = (ks * 4 + quad) ^ (r & 15);
                bf16x8 kf = *(const bf16x8*)(Ks + (r * 16 + pc) * 8);
                sc[nt] = __builtin_amdgcn_mfma_f32_16x16x32_bf16(qf[ks], kf, sc[nt], 0, 0, 0);
            }
        }
        // ---- causal mask (diagonal tile only)
        if (kt == qt) {
#pragma unroll
            for (int nt = 0; nt < 4; ++nt)
#pragma unroll
                for (int r = 0; r < 4; ++r) {
                    int col = k0 + nt * 16 + l16;
                    int row = q0 + w * 16 + quad * 4 + r;
                    if (col > row) sc[nt][r] = -1e30f;
                }
        }
        // ---- online softmax (row reduce across the 16 lanes of each quad)
        float rmax[4] = { -1e30f, -1e30f, -1e30f, -1e30f };
#pragma unroll
        for (int nt = 0; nt < 4; ++nt)
#pragma unroll
            for (int r = 0; r < 4; ++r) rmax[r] = fmaxf(rmax[r], sc[nt][r]);
#pragma unroll
        for (int r = 0; r < 4; ++r)
#pragma unroll
            for (int off = 1; off < 16; off <<= 1)
                rmax[r] = fmaxf(rmax[r], __shfl_xor(rmax[r], off));
        float alpha[4], rsum[4];
#pragma unroll
        for (int r = 0; r < 4; ++r) {
            float mnew = fmaxf(m_r[r], rmax[r]);
            alpha[r] = __expf(m_r[r] - mnew);
            m_r[r] = mnew;
            rsum[r] = 0.f;
        }
#pragma unroll
        for (int nt = 0; nt < 4; ++nt)
#pragma unroll
            for (int r = 0; r < 4; ++r) {
                float p = __expf(sc[nt][r] - m_r[r]);
                rsum[r] += p;
                // C layout (row=quad*4+r, col=nt*16+l16) -> Ps[row][key]
                Ps[w][(quad * 4 + r) * 72 + nt * 16 + l16] = f2bf(p);
            }
#pragma unroll
        for (int r = 0; r < 4; ++r) {
#pragma unroll
            for (int off = 1; off < 16; off <<= 1) rsum[r] += __shfl_xor(rsum[r], off);
            l_r[r] = l_r[r] * alpha[r] + rsum[r];
        }
#pragma unroll
        for (int nt = 0; nt < 8; ++nt)
#pragma unroll
            for (int r = 0; r < 4; ++r) o[nt][r] = o[nt][r] * alpha[r];

        // ---- O += P V  (same-wave LDS write->read is in-order; no barrier needed)
#pragma unroll
        for (int ks = 0; ks < 2; ++ks) {
            bf16x8 pf = *(const bf16x8*)(&Ps[w][l16 * 72 + ks * 32 + quad * 8]);
#pragma unroll
            for (int nt = 0; nt < 8; ++nt) {
                bf16x8 vf = *(const bf16x8*)(Vt + (nt * 16 + l16) * 72 + ks * 32 + quad * 8);
                o[nt] = __builtin_amdgcn_mfma_f32_16x16x32_bf16(pf, vf, o[nt], 0, 0, 0);
            }
        }
        __syncthreads();   // protect Ks/Vt before next tile's staging
    }

    // ---- normalize + store (token-major [tok][h*128+d] -> feeds O-projection)
#pragma unroll
    for (int r = 0; r < 4; ++r) {
        float inv = 1.0f / l_r[r];
        int row = q0 + w * 16 + quad * 4 + r;
#pragma unroll
        for (int nt = 0; nt < 8; ++nt)
            Out[(size_t)(b * SEQ + row) * DMODEL + h * DKH + nt * 16 + l16] = f2bf(o[nt][r] * inv);
    }
}

// ---------------------------------------------------------------- launch
extern "C" void kernel_launch(void* const* d_in, const int* in_sizes, int n_in,
                              void* d_out, int out_size, void* d_ws, size_t ws_size,
                              hipStream_t stream)
{
    const float* x    = (const float*)d_in[0];
    const float* wq_w = (const float*)d_in[1];
    const float* wq_b = (const float*)d_in[2];
    const float* wk_w = (const float*)d_in[3];
    const float* wk_b = (const float*)d_in[4];
    const float* wv_w = (const float*)d_in[5];
    const float* wv_b = (const float*)d_in[6];
    const float* wo_w = (const float*)d_in[7];
    const float* wo_b = (const float*)d_in[8];
    float* out = (float*)d_out;

    char* ws = (char*)d_ws;
    u16* XB  = (u16*)(ws);                      // 16 MiB, reused as attn output
    u16* WQB = (u16*)(ws + (16u << 20));
    u16* WKB = (u16*)(ws + (24u << 20));
    u16* WVB = (u16*)(ws + (32u << 20));
    u16* WOB = (u16*)(ws + (40u << 20));
    u16* QB  = (u16*)(ws + (48u << 20));
    u16* KB  = (u16*)(ws + (64u << 20));
    u16* VB  = (u16*)(ws + (80u << 20));

    // casts to bf16
    cast_f2b_kernel<<<8192, 256, 0, stream>>>(x,    XB,  (MTOK * DMODEL) / 4);
    cast_f2b_kernel<<<4096, 256, 0, stream>>>(wq_w, WQB, (DMODEL * DMODEL) / 4);
    cast_f2b_kernel<<<4096, 256, 0, stream>>>(wk_w, WKB, (DMODEL * DMODEL) / 4);
    cast_f2b_kernel<<<4096, 256, 0, stream>>>(wv_w, WVB, (DMODEL * DMODEL) / 4);
    cast_f2b_kernel<<<4096, 256, 0, stream>>>(wo_w, WOB, (DMODEL * DMODEL) / 4);

    dim3 ggrid(DMODEL / 128, MTOK / 128);   // (16, 32)
    gemm_bt<true><<<ggrid, 256, 0, stream>>>(XB, WQB, wq_b, QB, MTOK, DMODEL, DMODEL);
    gemm_bt<true><<<ggrid, 256, 0, stream>>>(XB, WKB, wk_b, KB, MTOK, DMODEL, DMODEL);
    gemm_bt<true><<<ggrid, 256, 0, stream>>>(XB, WVB, wv_b, VB, MTOK, DMODEL, DMODEL);

    rope_kernel<<<dim3((MTOK * NHEAD * 64) / 256, 2), 256, 0, stream>>>(QB, KB);

    attn_kernel<<<dim3(SEQ / 64, NBATCH * NHEAD), 256, 0, stream>>>(QB, KB, VB, XB);

    gemm_bt<false><<<ggrid, 256, 0, stream>>>(XB, WOB, wo_b, out, MTOK, DMODEL, DMODEL);
}

// Round 2
// 436.956 us; speedup vs baseline: 1.2940x; 1.2940x over previous
//
#include <hip/hip_runtime.h>

// MHA forward, MI355X/gfx950.
// B=2, S=2048, D_MODEL=2048, H=16, DK=128. All GEMMs bf16-MFMA (16x16x32),
// fp32 accumulate. Weights are W[e][d] == B^T ("gemm_bt" shape).
//
// Workspace layout (96 MiB):
//   [0,16M)   xb   : x cast to bf16  (later reused as attention output)
//   [16,24M)  wq_b16, [24,32M) wk_b16, [32,40M) wv_b16, [40,48M) wo_b16
//   [48,64M)  Q bf16 (token-major), [64,80M) K bf16 (token-major),
//   [80,96M)  V^T bf16: [b*2048 + h*128 + d][s]  (pre-transposed by V-GEMM)

#define DMODEL 2048
#define SEQ    2048
#define NHEAD  16
#define DKH    128
#define NBATCH 2
#define MTOK   (NBATCH*SEQ)   // 4096

typedef float  f32x4  __attribute__((ext_vector_type(4)));
typedef __bf16 bf16x8 __attribute__((ext_vector_type(8)));
typedef unsigned short      u16;
typedef unsigned short      u16x4 __attribute__((ext_vector_type(4)));

__device__ __forceinline__ float b2f(u16 u) {
    union { unsigned i; float f; } x; x.i = ((unsigned)u) << 16; return x.f;
}
__device__ __forceinline__ u16 f2bf(float f) {  // round-to-nearest-even
    union { float f; unsigned i; } x; x.f = f;
    unsigned r = x.i + 0x7fffu + ((x.i >> 16) & 1u);
    return (u16)(r >> 16);
}

// async global->LDS, 16B per lane; LDS dest is wave-uniform base + lane*16
__device__ __forceinline__ void load_lds16(const void* g, void* l) {
    __builtin_amdgcn_global_load_lds(
        (const __attribute__((address_space(1))) void*)g,
        (__attribute__((address_space(3))) void*)l, 16, 0, 0);
}

// ---------------------------------------------------------------- cast f32->bf16
__global__ void cast_f2b_kernel(const float* __restrict__ in, u16* __restrict__ out, int n4) {
    int i = blockIdx.x * blockDim.x + threadIdx.x;
    if (i >= n4) return;
    float4 f = ((const float4*)in)[i];
    uint2 o;
    o.x = (unsigned)f2bf(f.x) | ((unsigned)f2bf(f.y) << 16);
    o.y = (unsigned)f2bf(f.z) | ((unsigned)f2bf(f.w) << 16);
    ((uint2*)out)[i] = o;
}

// ---------------------------------------------------------------- GEMM (B^T form)
// C[M][N] = A[M][K] * W[N][K]^T + bias.  128x128 tile, BK=64, 4 waves (2x2),
// each wave 64x64 via 4x4 MFMA 16x16x32 tiles. LDS 16B chunks XOR-swizzled.
// MODE: 0 = f32 row-major out, 1 = bf16 row-major out,
//       2 = bf16 V^T out: VT[(b*2048 + col)][s]  (b = tokrow>>11, s = tokrow&2047)
template<int MODE>
__global__ __launch_bounds__(256) void gemm_bt(
    const u16* __restrict__ A, const u16* __restrict__ W,
    const float* __restrict__ bias, void* __restrict__ Cout,
    int M, int N, int K)
{
    __shared__ u16 As[128 * 64];
    __shared__ u16 Bs[128 * 64];
    const int tid  = threadIdx.x;
    const int lane = tid & 63;
    const int w    = tid >> 6;
    const int wm   = w >> 1, wn = w & 1;
    const int quad = lane >> 4, l16 = lane & 15;
    const int row0 = blockIdx.y * 128;
    const int col0 = blockIdx.x * 128;

    f32x4 acc[4][4] = {};

    for (int kt = 0; kt < K / 64; ++kt) {
        const int k0 = kt * 64;
#pragma unroll
        for (int i = 0; i < 4; ++i) {
            int cb = (i * 4 + w) * 64;        // wave-uniform physical chunk base
            int p  = cb + lane;               // physical 16B chunk this lane fills
            int r  = p >> 3;                  // tile row
            int cl = (p & 7) ^ (r & 7);       // logical chunk to fetch
            load_lds16(A + (size_t)(row0 + r) * K + k0 + cl * 8, (void*)(As + cb * 8));
            load_lds16(W + (size_t)(col0 + r) * K + k0 + cl * 8, (void*)(Bs + cb * 8));
        }
        __syncthreads();
#pragma unroll
        for (int ks = 0; ks < 2; ++ks) {
            bf16x8 af[4], bfr[4];
#pragma unroll
            for (int mi = 0; mi < 4; ++mi) {
                int r  = wm * 64 + mi * 16 + l16;
                int pc = (ks * 4 + quad) ^ (r & 7);
                af[mi] = *(const bf16x8*)(As + (r * 8 + pc) * 8);
            }
#pragma unroll
            for (int ni = 0; ni < 4; ++ni) {
                int r  = wn * 64 + ni * 16 + l16;
                int pc = (ks * 4 + quad) ^ (r & 7);
                bfr[ni] = *(const bf16x8*)(Bs + (r * 8 + pc) * 8);
            }
#pragma unroll
            for (int mi = 0; mi < 4; ++mi)
#pragma unroll
                for (int ni = 0; ni < 4; ++ni)
                    acc[mi][ni] = __builtin_amdgcn_mfma_f32_16x16x32_bf16(
                        af[mi], bfr[ni], acc[mi][ni], 0, 0, 0);
        }
        __syncthreads();
    }
    // epilogue: C/D layout col=lane&15, row=quad*4+reg  [m89/m91 verified]
#pragma unroll
    for (int mi = 0; mi < 4; ++mi) {
#pragma unroll
        for (int ni = 0; ni < 4; ++ni) {
            int col = col0 + wn * 64 + ni * 16 + l16;
            float bv = bias[col];
            if (MODE == 2) {
                int rowb = row0 + wm * 64 + mi * 16 + quad * 4;  // +r consecutive
                int bb = rowb >> 11, s = rowb & 2047;
                u16x4 pk;
#pragma unroll
                for (int r = 0; r < 4; ++r) pk[r] = f2bf(acc[mi][ni][r] + bv);
                *(u16x4*)((u16*)Cout + (size_t)(bb * 2048 + col) * 2048 + s) = pk;
            } else {
#pragma unroll
                for (int r = 0; r < 4; ++r) {
                    int row = row0 + wm * 64 + mi * 16 + quad * 4 + r;
                    float v = acc[mi][ni][r] + bv;
                    if (MODE == 1) ((u16*)Cout)[(size_t)row * N + col] = f2bf(v);
                    else           ((float*)Cout)[(size_t)row * N + col] = v;
                }
            }
        }
    }
}

// ---------------------------------------------------------------- RoPE (in-place)
__global__ void rope_kernel(u16* __restrict__ Q, u16* __restrict__ Kt) {
    int idx = blockIdx.x * blockDim.x + threadIdx.x;   // < MTOK*NHEAD*64
    u16* P      = blockIdx.y ? Kt : Q;
    float scale = blockIdx.y ? 1.0f : 0.08838834764831845f;  // 1/sqrt(128)
    int i   = idx & 63;          // frequency index
    int tok = idx >> 10;         // (h*64+i) packs into 10 bits
    int s   = tok & (SEQ - 1);
    unsigned pr = *(const unsigned*)(P + 2 * (size_t)idx);
    float e = b2f((u16)(pr & 0xffff)), o = b2f((u16)(pr >> 16));
    float inv_freq = exp2f(-13.287712379549449f * (float)i * (1.0f / 64.0f));
    float ang = (float)s * inv_freq;
    float c, sn;
    sincosf(ang, &sn, &c);
    float re = (e * c - o * sn) * scale;
    float ro = (e * sn + o * c) * scale;
    *(unsigned*)(P + 2 * (size_t)idx) = (unsigned)f2bf(re) | ((unsigned)f2bf(ro) << 16);
}

// ---------------------------------------------------------------- flash attention
// Paired-tile blocks for causal load balance: block (p, bh) has 8 waves;
// waves 0-3 process q-tile p, waves 4-7 process q-tile 31-p, SHARING the
// staged K and V^T tiles. All blocks resident (512 blocks, 2/CU); block
// durations span 17..32 tile-iterations instead of 1..32.
// K tile staged swizzled (16 chunks/row, ^r&15); V^T tile [d][key] staged
// swizzled (8 chunks/row, ^r&7) directly from the pre-transposed global V.
__global__ __launch_bounds__(512, 4) void attn_kernel(
    const u16* __restrict__ Q, const u16* __restrict__ Kg,
    const u16* __restrict__ VTg, u16* __restrict__ Out)
{
    const int p  = blockIdx.x;           // pair index 0..15
    const int bh = blockIdx.y;
    const int b  = bh >> 4, h = bh & 15;

    const int tid  = threadIdx.x;
    const int lane = tid & 63;
    const int w    = tid >> 6;           // 0..7
    const int half = w >> 2;             // 0 = low tile, 1 = high tile
    const int wsub = w & 3;
    const int quad = lane >> 4, l16 = lane & 15;

    const int q_hi  = 31 - p;
    const int my_qt = half ? q_hi : p;
    const int q0    = my_qt * 64;

    __shared__ u16 Ks[64 * 128];         // 16 KB, swizzle ^(r&15)
    __shared__ u16 Vt[128 * 64];         // 16 KB, [d][key], swizzle ^(r&7)
    __shared__ u16 Ps[8][16 * 72];       // 18 KB per-wave P buffers

    // Q fragments for this wave's 16 rows (A-operand: m=lane&15, k=quad*8+j)
    bf16x8 qf[4];
    const u16* qrow = Q + (size_t)(b * SEQ + q0 + wsub * 16 + l16) * DMODEL + h * DKH;
#pragma unroll
    for (int ks = 0; ks < 4; ++ks) qf[ks] = *(const bf16x8*)(qrow + ks * 32 + quad * 8);

    f32x4 o[8] = {};
    float m_r[4], l_r[4];
#pragma unroll
    for (int r = 0; r < 4; ++r) { m_r[r] = -1e30f; l_r[r] = 0.f; }

    for (int kt = 0; kt <= q_hi; ++kt) {
        const int k0 = kt * 64;
        // ---- stage K (1024 chunks, 512 threads -> 2 each)
#pragma unroll
        for (int i = 0; i < 2; ++i) {
            int cb = (i * 8 + w) * 64;
            int pc = cb + lane;
            int r  = pc >> 4;
            int cl = (pc & 15) ^ (r & 15);
            load_lds16(Kg + (size_t)(b * SEQ + k0 + r) * DMODEL + h * DKH + cl * 8,
                       (void*)(Ks + cb * 8));
        }
        // ---- stage V^T (1024 chunks; row = d, 8 chunks of keys per row)
#pragma unroll
        for (int i = 0; i < 2; ++i) {
            int cb = (i * 8 + w) * 64;
            int pc = cb + lane;
            int r  = pc >> 3;                 // d
            int cl = (pc & 7) ^ (r & 7);
            load_lds16(VTg + (size_t)(b * 2048 + h * DKH + r) * SEQ + k0 + cl * 8,
                       (void*)(Vt + cb * 8));
        }
        __syncthreads();

        if (kt <= my_qt) {
            // ---- S = Q K^T  (scale folded into Q)
            f32x4 sc[4] = {};
#pragma unroll
            for (int ks = 0; ks < 4; ++ks) {
#pragma unroll
                for (int nt = 0; nt < 4; ++nt) {
                    int r  = nt * 16 + l16;
                    int pc = (ks * 4 + quad) ^ (r & 15);
                    bf16x8 kf = *(const bf16x8*)(Ks + (r * 16 + pc) * 8);
                    sc[nt] = __builtin_amdgcn_mfma_f32_16x16x32_bf16(qf[ks], kf, sc[nt], 0, 0, 0);
                }
            }
            // ---- causal mask (diagonal tile only)
            if (kt == my_qt) {
#pragma unroll
                for (int nt = 0; nt < 4; ++nt)
#pragma unroll
                    for (int r = 0; r < 4; ++r) {
                        int col = k0 + nt * 16 + l16;
                        int row = q0 + wsub * 16 + quad * 4 + r;
                        if (col > row) sc[nt][r] = -1e30f;
                    }
            }
            // ---- online softmax (row reduce across 16 lanes of each quad)
            float rmax[4] = { -1e30f, -1e30f, -1e30f, -1e30f };
#pragma unroll
            for (int nt = 0; nt < 4; ++nt)
#pragma unroll
                for (int r = 0; r < 4; ++r) rmax[r] = fmaxf(rmax[r], sc[nt][r]);
#pragma unroll
            for (int r = 0; r < 4; ++r)
#pragma unroll
                for (int off = 1; off < 16; off <<= 1)
                    rmax[r] = fmaxf(rmax[r], __shfl_xor(rmax[r], off));
            float alpha[4], rsum[4];
#pragma unroll
            for (int r = 0; r < 4; ++r) {
                float mnew = fmaxf(m_r[r], rmax[r]);
                alpha[r] = __expf(m_r[r] - mnew);
                m_r[r] = mnew;
                rsum[r] = 0.f;
            }
#pragma unroll
            for (int nt = 0; nt < 4; ++nt)
#pragma unroll
                for (int r = 0; r < 4; ++r) {
                    float pv = __expf(sc[nt][r] - m_r[r]);
                    rsum[r] += pv;
                    Ps[w][(quad * 4 + r) * 72 + nt * 16 + l16] = f2bf(pv);
                }
#pragma unroll
            for (int r = 0; r < 4; ++r) {
#pragma unroll
                for (int off = 1; off < 16; off <<= 1) rsum[r] += __shfl_xor(rsum[r], off);
                l_r[r] = l_r[r] * alpha[r] + rsum[r];
            }
#pragma unroll
            for (int nt = 0; nt < 8; ++nt)
#pragma unroll
                for (int r = 0; r < 4; ++r) o[nt][r] = o[nt][r] * alpha[r];

            // ---- O += P V  (same-wave LDS write->read; no barrier needed)
#pragma unroll
            for (int ks = 0; ks < 2; ++ks) {
                bf16x8 pf = *(const bf16x8*)(&Ps[w][l16 * 72 + ks * 32 + quad * 8]);
#pragma unroll
                for (int nt = 0; nt < 8; ++nt) {
                    int r  = nt * 16 + l16;                  // d
                    int pc = (ks * 4 + quad) ^ (r & 7);
                    bf16x8 vf = *(const bf16x8*)(Vt + r * 64 + pc * 8);
                    o[nt] = __builtin_amdgcn_mfma_f32_16x16x32_bf16(pf, vf, o[nt], 0, 0, 0);
                }
            }
        }
        __syncthreads();   // protect Ks/Vt before next tile's staging
    }

    // ---- normalize + store (token-major [tok][h*128+d] -> feeds O-projection)
#pragma unroll
    for (int r = 0; r < 4; ++r) {
        float inv = 1.0f / l_r[r];
        int row = q0 + wsub * 16 + quad * 4 + r;
#pragma unroll
        for (int nt = 0; nt < 8; ++nt)
            Out[(size_t)(b * SEQ + row) * DMODEL + h * DKH + nt * 16 + l16] = f2bf(o[nt][r] * inv);
    }
}

// ---------------------------------------------------------------- launch
extern "C" void kernel_launch(void* const* d_in, const int* in_sizes, int n_in,
                              void* d_out, int out_size, void* d_ws, size_t ws_size,
                              hipStream_t stream)
{
    const float* x    = (const float*)d_in[0];
    const float* wq_w = (const float*)d_in[1];
    const float* wq_b = (const float*)d_in[2];
    const float* wk_w = (const float*)d_in[3];
    const float* wk_b = (const float*)d_in[4];
    const float* wv_w = (const float*)d_in[5];
    const float* wv_b = (const float*)d_in[6];
    const float* wo_w = (const float*)d_in[7];
    const float* wo_b = (const float*)d_in[8];
    float* out = (float*)d_out;

    char* ws = (char*)d_ws;
    u16* XB  = (u16*)(ws);                      // 16 MiB, reused as attn output
    u16* WQB = (u16*)(ws + (16u << 20));
    u16* WKB = (u16*)(ws + (24u << 20));
    u16* WVB = (u16*)(ws + (32u << 20));
    u16* WOB = (u16*)(ws + (40u << 20));
    u16* QB  = (u16*)(ws + (48u << 20));
    u16* KB  = (u16*)(ws + (64u << 20));
    u16* VTB = (u16*)(ws + (80u << 20));        // V^T: [b*2048+h*128+d][s]

    cast_f2b_kernel<<<8192, 256, 0, stream>>>(x,    XB,  (MTOK * DMODEL) / 4);
    cast_f2b_kernel<<<4096, 256, 0, stream>>>(wq_w, WQB, (DMODEL * DMODEL) / 4);
    cast_f2b_kernel<<<4096, 256, 0, stream>>>(wk_w, WKB, (DMODEL * DMODEL) / 4);
    cast_f2b_kernel<<<4096, 256, 0, stream>>>(wv_w, WVB, (DMODEL * DMODEL) / 4);
    cast_f2b_kernel<<<4096, 256, 0, stream>>>(wo_w, WOB, (DMODEL * DMODEL) / 4);

    dim3 ggrid(DMODEL / 128, MTOK / 128);   // (16, 32)
    gemm_bt<1><<<ggrid, 256, 0, stream>>>(XB, WQB, wq_b, QB,  MTOK, DMODEL, DMODEL);
    gemm_bt<1><<<ggrid, 256, 0, stream>>>(XB, WKB, wk_b, KB,  MTOK, DMODEL, DMODEL);
    gemm_bt<2><<<ggrid, 256, 0, stream>>>(XB, WVB, wv_b, VTB, MTOK, DMODEL, DMODEL);

    rope_kernel<<<dim3((MTOK * NHEAD * 64) / 256, 2), 256, 0, stream>>>(QB, KB);

    attn_kernel<<<dim3(16, NBATCH * NHEAD), 512, 0, stream>>>(QB, KB, VTB, XB);

    gemm_bt<0><<<ggrid, 256, 0, stream>>>(XB, WOB, wo_b, out, MTOK, DMODEL, DMODEL);
}